// Round 14
// baseline (180.934 us; speedup 1.0000x reference)
//
#include <hip/hip_runtime.h>
#include <stdint.h>

using f16 = _Float16;

typedef _Float16 f16x8 __attribute__((ext_vector_type(8)));
typedef _Float16 f16x4 __attribute__((ext_vector_type(4)));
typedef float f32x4 __attribute__((ext_vector_type(4)));

#define LOG2E 1.44269504088896340736f

__device__ __forceinline__ f16 f2h(float f) { return (f16)f; }  // RNE

#if __has_builtin(__builtin_amdgcn_exp2f)
__device__ __forceinline__ float fexp2(float x) { return __builtin_amdgcn_exp2f(x); }
#else
__device__ __forceinline__ float fexp2(float x) { return exp2f(x); }
#endif

typedef __attribute__((address_space(1))) const uint32_t gu32;
typedef __attribute__((address_space(3))) uint32_t lu32;

__device__ __forceinline__ void dma16(const void* g, void* l) {
  // global->LDS DMA, 16 B/lane; LDS dest = wave-uniform base (+ lane*16 by HW)
  __builtin_amdgcn_global_load_lds((gu32*)g, (lu32*)l, 16, 0, 0);
}

__device__ __forceinline__ f16x8 cvt8(const float* p) {
  const float4 a = *(const float4*)p;
  const float4 b = *(const float4*)(p + 4);
  f16x8 r;
  r[0] = (f16)a.x; r[1] = (f16)a.y; r[2] = (f16)a.z; r[3] = (f16)a.w;
  r[4] = (f16)b.x; r[5] = (f16)b.y; r[6] = (f16)b.z; r[7] = (f16)b.w;
  return r;
}

// B=4, C=64, N=4096.  Global in/out FP32; internal tensor-core path FP16.
// ws layout (bytes):
//   0     qa  f16 [4][4096][64]      (2 MB)  q*log2e, position-major
//   2 MB  ka2 f16 [4][8][4096][8]    (2 MB)  K channel-chunked: [b][c8][key][8c]
//   4 MB  va3 f16 [4][1024][64][4]   (2 MB)  V key-chunked:     [b][k4][c][4k]
//   6 MB  y0  f32 [4][64][4096]      (4 MB)  gamma*attn_out, pre-BN
//   10 MB stats: gs1[64] | gs2[64]   (zeroed by pre block 0)

// ---------------------------------------------------------------------------
// pre: conv1d q/k over channels, v = vw@x+vb via MFMA.
// ---------------------------------------------------------------------------
__global__ __launch_bounds__(256, 2) void pam_pre(
    const float* __restrict__ x, const float* __restrict__ qw,
    const float* __restrict__ kw, const float* __restrict__ vw,
    const float* __restrict__ vb,
    f16* __restrict__ qa, f16* __restrict__ ka2, f16* __restrict__ va3,
    float* __restrict__ gz)
{
  __shared__ alignas(16) f16 xt[32 * 72];   // xt[n][c] f16, row stride 72
  const int tid = threadIdx.x;
  const int b = blockIdx.x >> 7;
  const int n0 = (blockIdx.x & 127) << 5;
  const int lane = tid & 63;
  const int wv = tid >> 6;
  const int quad = lane >> 4, l15 = lane & 15;

  if (blockIdx.x == 0 && tid < 128) gz[tid] = 0.f;   // gs1|gs2 zero-init

  {
    const int c = tid >> 2;
    const int j0 = (tid & 3) << 3;
    const float* xp = x + ((size_t)(b * 64 + c) << 12) + n0 + j0;
    const float4 v0 = *(const float4*)xp;
    const float4 v1 = *(const float4*)(xp + 4);
    xt[(j0 + 0) * 72 + c] = f2h(v0.x);
    xt[(j0 + 1) * 72 + c] = f2h(v0.y);
    xt[(j0 + 2) * 72 + c] = f2h(v0.z);
    xt[(j0 + 3) * 72 + c] = f2h(v0.w);
    xt[(j0 + 4) * 72 + c] = f2h(v1.x);
    xt[(j0 + 5) * 72 + c] = f2h(v1.y);
    xt[(j0 + 6) * 72 + c] = f2h(v1.z);
    xt[(j0 + 7) * 72 + c] = f2h(v1.w);
  }
  __syncthreads();

  const float qw0 = qw[0], qw1 = qw[1], qw2 = qw[2];
  const float kw0 = kw[0], kw1 = kw[1], kw2 = kw[2];
  for (int p = 0; p < 8; ++p) {
    const int c = lane;
    const int jr = (p << 2) + wv;
    const int n = n0 + jr;
    const float xm = (c > 0) ? (float)xt[jr * 72 + c - 1] : 0.f;
    const float x0 = (float)xt[jr * 72 + c];
    const float xp = (c < 63) ? (float)xt[jr * 72 + c + 1] : 0.f;
    const float qv = (qw0 * xm + qw1 * x0 + qw2 * xp) * LOG2E;  // log2-domain
    const float kv = kw0 * xm + kw1 * x0 + kw2 * xp;
    qa[((size_t)((b << 12) + n) << 6) + c] = f2h(qv);
    ka2[((size_t)(b * 8 + (c >> 3)) << 15) + (n << 3) + (c & 7)] = f2h(kv);
  }

  {
    const f16x8 a0 = cvt8(vw + (wv * 16 + l15) * 64 + quad * 8);
    const f16x8 a1 = cvt8(vw + (wv * 16 + l15) * 64 + quad * 8 + 32);
    f32x4 acc[2];
    for (int st = 0; st < 2; ++st) {
      const f16x8 b0 = *(const f16x8*)&xt[(st * 16 + l15) * 72 + quad * 8];
      const f16x8 b1 = *(const f16x8*)&xt[(st * 16 + l15) * 72 + quad * 8 + 32];
      f32x4 z = {0.f, 0.f, 0.f, 0.f};
      z = __builtin_amdgcn_mfma_f32_16x16x32_f16(a0, b0, z, 0, 0, 0);
      acc[st] = __builtin_amdgcn_mfma_f32_16x16x32_f16(a1, b1, z, 0, 0, 0);
    }
    const int cobase = wv * 16 + quad * 4;
    for (int st = 0; st < 2; ++st)
      for (int r = 0; r < 4; ++r) {
        const int co = cobase + r;
        const int n = n0 + st * 16 + l15;
        const float val = acc[st][r] + vb[co];
        // va3[b][n>>2][co][n&3]
        va3[(((size_t)(b * 1024 + (n >> 2))) << 8) + (co << 2) + (n & 3)] = f2h(val);
      }
  }
}

// ---------------------------------------------------------------------------
// attention v14: one 1024-thread block/CU (grid 256). Waves = (qh 0..1, ks
// 0..7): 2 q-tiles x 32-key slice of 256-key tiles (16 iters). KEY CHANGES vs
// r13 (which tied r12 -> LDS-pipe bound):
//  (1) NO P LDS round-trip: v_mfma 16x16x16 A-layout (k=quad*4+j) ==
//      S^T C-layout (key=quad*4+r), so P feeds PV directly from registers.
//  (2) 2x (not 4x) K/V fragment-read redundancy via 256-key tiles (capacity
//      freed by deleting pbuf). V in [k4][c][4] chunks -> conflict-free b64.
// ---------------------------------------------------------------------------
__global__ __launch_bounds__(1024, 4) void pam_attn(
    const f16* __restrict__ qa, const f16* __restrict__ ka2,
    const f16* __restrict__ va3, const float* __restrict__ gam,
    float* __restrict__ y0, float* __restrict__ gs1, float* __restrict__ gs2)
{
  __shared__ alignas(16) f16 kbuf[2][16384];   // [c8][256key][8c], 32 KB each
  __shared__ alignas(16) f16 vbuf[2][16384];   // [64 k4][64 c][4k], 32 KB each
  __shared__ float ldsO[64 * 65];
  __shared__ float ldsM[8][64], ldsL[8][64], ldsMg[64], ldsInv[64];

  const int tid = threadIdx.x;
  const int wv = tid >> 6, lane = tid & 63;
  const int quad = lane >> 4, l15 = lane & 15;
  const int ks = wv & 7, qh = wv >> 3;
  const int b = blockIdx.x & 3;
  const int qb = blockIdx.x >> 2;          // 0..63
  const int qb0 = qb << 6;
  const int phase = qb & 15;               // anti-convoy rotation (16 tiles)

  for (int i = tid; i < 64 * 65; i += 1024) ldsO[i] = 0.f;

  const int bn = b << 12;
  // Q fragments: 2 q-tiles (qh*2+qt), ch-halves
  f16x8 bq[2][2];
  for (int qt = 0; qt < 2; ++qt) {
    const int q = qb0 + (qh * 2 + qt) * 16 + l15;
    const f16* qp = qa + ((size_t)(bn + q) << 6) + quad * 8;
    bq[qt][0] = *(const f16x8*)qp;
    bq[qt][1] = *(const f16x8*)(qp + 32);
  }

  // staging bases. K: wave covers c8 = wv>>1, keys (wv&1)*128 + r*64 + lane.
  const int k_c8 = wv >> 1;
  const int k_koff = (wv & 1) << 7;
  const f16* kg0 = ka2 + (((size_t)(b * 8 + k_c8)) << 15) + (k_koff << 3) + (lane << 3);
  const int kl_base = k_c8 * 2048 + (k_koff << 3);
  // V: wave covers 16 consecutive (k4,c)-chunk pairs per round.
  const f16* vg0 = va3 + ((size_t)b << 18) + ((wv * 64 + lane) << 3);
  const int vl_base = wv << 9;

  f32x4 o[2][4] = {};
  float m[2] = {-1e30f, -1e30f};
  float lp[2] = {0.f, 0.f};

  // stage tile 'phase' into buf 0
  dma16(kg0 + ((size_t)phase << 11),        kbuf[0] + kl_base);
  dma16(kg0 + ((size_t)phase << 11) + 512,  kbuf[0] + kl_base + 512);
  dma16(vg0 + ((size_t)phase << 14),        vbuf[0] + vl_base);
  dma16(vg0 + ((size_t)phase << 14) + 8192, vbuf[0] + vl_base + 8192);
  __syncthreads();

#pragma unroll 1
  for (int kt = 0; kt < 16; ++kt) {
    const int cur = kt & 1;
    {
      const int tn = (kt + 1 + phase) & 15;
      f16* kd = kbuf[cur ^ 1] + kl_base;
      f16* vd = vbuf[cur ^ 1] + vl_base;
      dma16(kg0 + ((size_t)tn << 11),        kd);
      dma16(kg0 + ((size_t)tn << 11) + 512,  kd + 512);
      dma16(vg0 + ((size_t)tn << 14),        vd);
      dma16(vg0 + ((size_t)tn << 14) + 8192, vd + 8192);
    }

    const f16* kc = kbuf[cur];
    const f16* vc = vbuf[cur];
    f16x8 ak[2][2];
    for (int mt = 0; mt < 2; ++mt) {
      const int keyL = (ks * 32 + mt * 16 + l15) << 3;
      ak[mt][0] = *(const f16x8*)(kc + quad * 2048 + keyL);
      ak[mt][1] = *(const f16x8*)(kc + (4 + quad) * 2048 + keyL);
    }

    f16x4 a[2][2];   // P fragments, straight from registers (no LDS!)
    for (int qt = 0; qt < 2; ++qt) {
      f32x4 s0, s1;
      {
        f32x4 z = {0.f, 0.f, 0.f, 0.f};
        z = __builtin_amdgcn_mfma_f32_16x16x32_f16(ak[0][0], bq[qt][0], z, 0, 0, 0);
        s0 = __builtin_amdgcn_mfma_f32_16x16x32_f16(ak[0][1], bq[qt][1], z, 0, 0, 0);
      }
      {
        f32x4 z = {0.f, 0.f, 0.f, 0.f};
        z = __builtin_amdgcn_mfma_f32_16x16x32_f16(ak[1][0], bq[qt][0], z, 0, 0, 0);
        s1 = __builtin_amdgcn_mfma_f32_16x16x32_f16(ak[1][1], bq[qt][1], z, 0, 0, 0);
      }

      float tmax = fmaxf(fmaxf(fmaxf(s0[0], s0[1]), fmaxf(s0[2], s0[3])),
                         fmaxf(fmaxf(s1[0], s1[1]), fmaxf(s1[2], s1[3])));
      tmax = fmaxf(tmax, __shfl_xor(tmax, 16, 64));
      tmax = fmaxf(tmax, __shfl_xor(tmax, 32, 64));
      const bool upd = tmax > m[qt];
      const float mnew = upd ? tmax : m[qt];

      float tsum = 0.f;
      {
        const float p0 = fexp2(s0[0] - mnew);
        const float p1 = fexp2(s0[1] - mnew);
        const float p2 = fexp2(s0[2] - mnew);
        const float p3 = fexp2(s0[3] - mnew);
        tsum += (p0 + p1) + (p2 + p3);
        a[qt][0][0] = f2h(p0); a[qt][0][1] = f2h(p1);
        a[qt][0][2] = f2h(p2); a[qt][0][3] = f2h(p3);
      }
      {
        const float p0 = fexp2(s1[0] - mnew);
        const float p1 = fexp2(s1[1] - mnew);
        const float p2 = fexp2(s1[2] - mnew);
        const float p3 = fexp2(s1[3] - mnew);
        tsum += (p0 + p1) + (p2 + p3);
        a[qt][1][0] = f2h(p0); a[qt][1][1] = f2h(p1);
        a[qt][1][2] = f2h(p2); a[qt][1][3] = f2h(p3);
      }

      if (__any(upd)) {
        const float alpha = fexp2(m[qt] - mnew);   // quad-uniform at l15=q
        lp[qt] = lp[qt] * alpha + tsum;
        const int srcbase = (lane & 48) + ((lane >> 4) << 2);
        for (int r = 0; r < 4; ++r) {
          const float ar = __shfl(alpha, srcbase + r, 64);
          for (int ct = 0; ct < 4; ++ct) o[qt][ct][r] *= ar;
        }
      } else {
        lp[qt] += tsum;
      }
      m[qt] = mnew;
    }

    // O += P*V via K=16 MFMA (A = P registers; B = V b64 chunks, read once)
    for (int ct = 0; ct < 4; ++ct) {
      const int cb = ((ct * 16 + l15) << 2);
      const f16x4 bv0 = *(const f16x4*)(vc + ((ks * 8 + quad) << 8) + cb);
      const f16x4 bv1 = *(const f16x4*)(vc + ((ks * 8 + 4 + quad) << 8) + cb);
      for (int qt = 0; qt < 2; ++qt) {
        o[qt][ct] = __builtin_amdgcn_mfma_f32_16x16x16f16(a[qt][0], bv0, o[qt][ct], 0, 0, 0);
        o[qt][ct] = __builtin_amdgcn_mfma_f32_16x16x16f16(a[qt][1], bv1, o[qt][ct], 0, 0, 0);
      }
    }
    __syncthreads();   // DMA landed + all waves done with buffers
  }

  // publish per-wave online state (m quad-uniform; lp reduced across quads)
  for (int qt = 0; qt < 2; ++qt) {
    float v = lp[qt];
    v += __shfl_xor(v, 16, 64);
    v += __shfl_xor(v, 32, 64);
    if (quad == 0) {
      ldsM[ks][(qh * 2 + qt) * 16 + l15] = m[qt];
      ldsL[ks][(qh * 2 + qt) * 16 + l15] = v;
    }
  }
  __syncthreads();

  // per-query global max + denom (8 key-slices)
  if (tid < 64) {
    float M = ldsM[0][tid];
    for (int w = 1; w < 8; ++w) M = fmaxf(M, ldsM[w][tid]);
    float lt = 0.f;
    for (int w = 0; w < 8; ++w) lt += ldsL[w][tid] * fexp2(ldsM[w][tid] - M);
    ldsMg[tid] = M;
    ldsInv[tid] = 1.f / lt;
  }
  __syncthreads();

  // m-aware merge of partial O across the 8 key-split waves
  for (int qt = 0; qt < 2; ++qt) {
    for (int r = 0; r < 4; ++r) {
      const int q = (qh * 2 + qt) * 16 + quad * 4 + r;
      const float sc = fexp2(ldsM[ks][q] - ldsMg[q]);
      for (int ct = 0; ct < 4; ++ct)
        atomicAdd(&ldsO[q * 65 + ct * 16 + l15], o[qt][ct][r] * sc);
    }
  }
  __syncthreads();

  // epilogue: y0[b][c][n] = gamma * O / l ; BN partial sums
  const float g = gam[0];
  {
    const int c = tid >> 4;              // 0..63
    const int q0 = (tid & 15) << 2;      // 0..60
    float4 v4;
    float* vp = &v4.x;
    float s1 = 0.f, s2 = 0.f;
    for (int r = 0; r < 4; ++r) {
      const float val = g * ldsO[(q0 + r) * 65 + c] * ldsInv[q0 + r];
      vp[r] = val; s1 += val; s2 += val * val;
    }
    *(float4*)(y0 + ((size_t)(b * 64 + c) << 12) + qb0 + q0) = v4;
    s1 += __shfl_xor(s1, 1, 64);
    s2 += __shfl_xor(s2, 1, 64);
    s1 += __shfl_xor(s1, 2, 64);
    s2 += __shfl_xor(s2, 2, 64);
    s1 += __shfl_xor(s1, 4, 64);
    s2 += __shfl_xor(s2, 4, 64);
    s1 += __shfl_xor(s1, 8, 64);
    s2 += __shfl_xor(s2, 8, 64);
    if (l15 == 0) {
      atomicAdd(&gs1[c], s1);
      atomicAdd(&gs2[c], s2);
    }
  }
}

// ---------------------------------------------------------------------------
// apply: BN(scale/shift from gs1/gs2) + residual.
// ---------------------------------------------------------------------------
__global__ __launch_bounds__(256, 2) void pam_apply(
    const float* __restrict__ y0, const float* __restrict__ x,
    const float* __restrict__ gs1, const float* __restrict__ gs2,
    const float* __restrict__ bnw, const float* __restrict__ bnb,
    float* __restrict__ out)
{
  const int i = (blockIdx.x * 256 + threadIdx.x) << 2;   // 4 elems/thread
  const int c = (i >> 12) & 63;
  const float inv_n = 1.f / 16384.f;
  const float mean = gs1[c] * inv_n;
  const float var = fmaxf(gs2[c] * inv_n - mean * mean, 0.f);
  const float sc = bnw[c] * rsqrtf(var + 1e-5f);
  const float sh = bnb[c] - mean * sc;
  const float4 y = *(const float4*)(y0 + i);
  const float4 xv = *(const float4*)(x + i);
  float4 r;
  r.x = y.x * sc + sh + xv.x;
  r.y = y.y * sc + sh + xv.y;
  r.z = y.z * sc + sh + xv.z;
  r.w = y.w * sc + sh + xv.w;
  *(float4*)(out + i) = r;
}

// ---------------------------------------------------------------------------
extern "C" void kernel_launch(void* const* d_in, const int* in_sizes, int n_in,
                              void* d_out, int out_size, void* d_ws, size_t ws_size,
                              hipStream_t stream)
{
  (void)in_sizes; (void)n_in; (void)out_size; (void)ws_size;
  const float* x   = (const float*)d_in[0];
  const float* qw  = (const float*)d_in[1];
  const float* kw  = (const float*)d_in[2];
  const float* vw  = (const float*)d_in[3];
  const float* vb  = (const float*)d_in[4];
  const float* gam = (const float*)d_in[5];
  const float* bnw = (const float*)d_in[6];
  const float* bnb = (const float*)d_in[7];

  char* ws = (char*)d_ws;
  f16*   qa  = (f16*)(ws);
  f16*   ka2 = (f16*)(ws + (2u << 20));
  f16*   va3 = (f16*)(ws + (4u << 20));
  float* y0  = (float*)(ws + (6u << 20));
  float* gs1 = (float*)(ws + (10u << 20));          // 64 floats
  float* gs2 = (float*)(ws + (10u << 20) + 256);    // 64 floats (contiguous)

  pam_pre  <<<512, 256, 0, stream>>>(x, qw, kw, vw, vb, qa, ka2, va3, gs1);
  pam_attn <<<256, 1024, 0, stream>>>(qa, ka2, va3, gam, y0, gs1, gs2);
  pam_apply<<<1024, 256, 0, stream>>>(y0, x, gs1, gs2, bnw, bnb, (float*)d_out);
}

// Round 16
// 152.881 us; speedup vs baseline: 1.1835x; 1.1835x over previous
//
#include <hip/hip_runtime.h>
#include <stdint.h>

using f16 = _Float16;

typedef _Float16 f16x8 __attribute__((ext_vector_type(8)));
typedef _Float16 f16x4 __attribute__((ext_vector_type(4)));
typedef float f32x4 __attribute__((ext_vector_type(4)));

#define LOG2E 1.44269504088896340736f

__device__ __forceinline__ f16 f2h(float f) { return (f16)f; }  // RNE

#if __has_builtin(__builtin_amdgcn_exp2f)
__device__ __forceinline__ float fexp2(float x) { return __builtin_amdgcn_exp2f(x); }
#else
__device__ __forceinline__ float fexp2(float x) { return exp2f(x); }
#endif

typedef __attribute__((address_space(1))) const uint32_t gu32;
typedef __attribute__((address_space(3))) uint32_t lu32;

__device__ __forceinline__ void dma16(const void* g, void* l) {
  // global->LDS DMA, 16 B/lane. NOTE: global source is PER-LANE (caller must
  // include lane*16B); only the LDS dest is auto-strided lane*16 by HW.
  __builtin_amdgcn_global_load_lds((gu32*)g, (lu32*)l, 16, 0, 0);
}

__device__ __forceinline__ f16x8 cvt8(const float* p) {
  const float4 a = *(const float4*)p;
  const float4 b = *(const float4*)(p + 4);
  f16x8 r;
  r[0] = (f16)a.x; r[1] = (f16)a.y; r[2] = (f16)a.z; r[3] = (f16)a.w;
  r[4] = (f16)b.x; r[5] = (f16)b.y; r[6] = (f16)b.z; r[7] = (f16)b.w;
  return r;
}

// B=4, C=64, N=4096.  Global in/out FP32; internal tensor-core path FP16.
// ws layout (bytes):
//   0     qa  f16 [4][4096][64]      (2 MB)  q*log2e, position-major
//   2 MB  ka2 f16 [4][8][4096][8]    (2 MB)  K channel-chunked: [b][c8][key][8c]
//   4 MB  va3 f16 [4][1024][64][4]   (2 MB)  V key-chunked:     [b][k4][c][4k]
//   6 MB  y0  f32 [4][64][4096]      (4 MB)  gamma*attn_out, pre-BN
//   10 MB stats: gs1[64] | gs2[64]   (zeroed by pre block 0)

// ---------------------------------------------------------------------------
// pre: conv1d q/k over channels, v = vw@x+vb via MFMA.
// grid 1024 = (b, n-tile of 16) -> 4 blocks/CU.
// ---------------------------------------------------------------------------
__global__ __launch_bounds__(256, 2) void pam_pre(
    const float* __restrict__ x, const float* __restrict__ qw,
    const float* __restrict__ kw, const float* __restrict__ vw,
    const float* __restrict__ vb,
    f16* __restrict__ qa, f16* __restrict__ ka2, f16* __restrict__ va3,
    float* __restrict__ gz)
{
  __shared__ alignas(16) f16 xt[16 * 72];   // xt[n][c] f16, row stride 72
  const int tid = threadIdx.x;
  const int b = blockIdx.x >> 8;
  const int n0 = (blockIdx.x & 255) << 4;
  const int lane = tid & 63;
  const int wv = tid >> 6;
  const int quad = lane >> 4, l15 = lane & 15;

  if (blockIdx.x == 0 && tid < 128) gz[tid] = 0.f;   // gs1|gs2 zero-init

  // stage x[b][c][n0:+16] (fp32) transposed into xt[n][c] (f16)
  {
    const int c = tid >> 2;
    const int j0 = (tid & 3) << 2;
    const float4 v0 = *(const float4*)(x + ((size_t)(b * 64 + c) << 12) + n0 + j0);
    xt[(j0 + 0) * 72 + c] = f2h(v0.x);
    xt[(j0 + 1) * 72 + c] = f2h(v0.y);
    xt[(j0 + 2) * 72 + c] = f2h(v0.z);
    xt[(j0 + 3) * 72 + c] = f2h(v0.w);
  }
  __syncthreads();

  // conv over channel axis (SAME, zero pad)
  const float qw0 = qw[0], qw1 = qw[1], qw2 = qw[2];
  const float kw0 = kw[0], kw1 = kw[1], kw2 = kw[2];
  for (int p = 0; p < 4; ++p) {
    const int c = lane;
    const int jr = (p << 2) + wv;
    const int n = n0 + jr;
    const float xm = (c > 0) ? (float)xt[jr * 72 + c - 1] : 0.f;
    const float x0 = (float)xt[jr * 72 + c];
    const float xp = (c < 63) ? (float)xt[jr * 72 + c + 1] : 0.f;
    const float qv = (qw0 * xm + qw1 * x0 + qw2 * xp) * LOG2E;  // log2-domain
    const float kv = kw0 * xm + kw1 * x0 + kw2 * xp;
    qa[((size_t)((b << 12) + n) << 6) + c] = f2h(qv);
    ka2[((size_t)(b * 8 + (c >> 3)) << 15) + (n << 3) + (c & 7)] = f2h(kv);
  }

  // v[c][n] = vw @ x + vb via mfma (wave wv -> c rows [16wv,+16))
  {
    const f16x8 a0 = cvt8(vw + (wv * 16 + l15) * 64 + quad * 8);
    const f16x8 a1 = cvt8(vw + (wv * 16 + l15) * 64 + quad * 8 + 32);
    const f16x8 b0 = *(const f16x8*)&xt[l15 * 72 + quad * 8];
    const f16x8 b1 = *(const f16x8*)&xt[l15 * 72 + quad * 8 + 32];
    f32x4 z = {0.f, 0.f, 0.f, 0.f};
    z = __builtin_amdgcn_mfma_f32_16x16x32_f16(a0, b0, z, 0, 0, 0);
    z = __builtin_amdgcn_mfma_f32_16x16x32_f16(a1, b1, z, 0, 0, 0);
    const int cobase = wv * 16 + quad * 4;
    for (int r = 0; r < 4; ++r) {
      const int co = cobase + r;
      const int n = n0 + l15;
      const float val = z[r] + vb[co];
      // va3[b][n>>2][co][n&3]
      va3[(((size_t)(b * 1024 + (n >> 2))) << 8) + (co << 2) + (n & 3)] = f2h(val);
    }
  }
}

// ---------------------------------------------------------------------------
// attention v16 = v15 + the missing PER-LANE source offset on the DMA bases
// (r15 bug: all lanes sourced the same 16 B -> garbage tiles, absmax 6.68).
// 512-thread blocks, two blocks co-resident per CU (LDS ~75 KB): two
// independent barrier domains overlap each other's vmcnt/barrier drains.
// Waves = (qh 0..1, ks 0..3): 32 q, 4-way key split, 128-key tiles, 32 iters.
// DMA staging, P in registers (16x16x16 PV). Grid 512 (4 b x 128 qb).
// ---------------------------------------------------------------------------
__global__ __launch_bounds__(512, 2) void pam_attn(
    const f16* __restrict__ qa, const f16* __restrict__ ka2,
    const f16* __restrict__ va3, const float* __restrict__ gam,
    float* __restrict__ y0, float* __restrict__ gs1, float* __restrict__ gs2)
{
  __shared__ alignas(16) f16 kbuf[2][8192];   // [c8][128key][8c], 16 KB each
  __shared__ alignas(16) f16 vbuf[2][8192];   // [32 k4][64 c][4k], 16 KB each
  __shared__ float ldsO[32 * 65];
  __shared__ float ldsM[4][32], ldsL[4][32], ldsMg[32], ldsInv[32];

  const int tid = threadIdx.x;
  const int wv = tid >> 6, lane = tid & 63;
  const int quad = lane >> 4, l15 = lane & 15;
  const int ks = wv & 3, qh = wv >> 2;
  const int b = blockIdx.x & 3;
  const int qb = blockIdx.x >> 2;          // 0..127
  const int qb0 = qb << 5;
  const int phase = qb & 31;               // anti-convoy rotation (32 tiles)

  for (int i = tid; i < 32 * 65; i += 512) ldsO[i] = 0.f;

  const int bn = b << 12;
  // Q fragments for this wave's q-tile
  f16x8 bq0, bq1;
  {
    const int q = qb0 + qh * 16 + l15;
    const f16* qp = qa + ((size_t)(bn + q) << 6) + quad * 8;
    bq0 = *(const f16x8*)qp;
    bq1 = *(const f16x8*)(qp + 32);
  }

  // staging bases (PER-LANE source: + lane*8 f16 = 16 B/lane).
  // K: wave wv covers c8-group wv (128 keys x 8c = 2 KB per tile).
  // V: wave wv covers k4-chunks [wv*4, +4) (2 KB per tile).
  const f16* kg0 = ka2 + (((size_t)(b * 8 + wv)) << 15) + (lane << 3);
  const f16* vg0 = va3 + ((size_t)b << 18) + (wv << 10) + (lane << 3);

  f32x4 o[4] = {};
  float m = -1e30f, lp = 0.f;

  // stage tile 'phase' into buf 0
  dma16(kg0 + ((size_t)phase << 10),       kbuf[0] + (wv << 10));
  dma16(kg0 + ((size_t)phase << 10) + 512, kbuf[0] + (wv << 10) + 512);
  dma16(vg0 + ((size_t)phase << 13),       vbuf[0] + (wv << 10));
  dma16(vg0 + ((size_t)phase << 13) + 512, vbuf[0] + (wv << 10) + 512);
  __syncthreads();

#pragma unroll 1
  for (int kt = 0; kt < 32; ++kt) {
    const int cur = kt & 1;
    {
      const int tn = (kt + 1 + phase) & 31;
      f16* kd = kbuf[cur ^ 1] + (wv << 10);
      f16* vd = vbuf[cur ^ 1] + (wv << 10);
      dma16(kg0 + ((size_t)tn << 10),       kd);
      dma16(kg0 + ((size_t)tn << 10) + 512, kd + 512);
      dma16(vg0 + ((size_t)tn << 13),       vd);
      dma16(vg0 + ((size_t)tn << 13) + 512, vd + 512);
    }

    const f16* kc = kbuf[cur];
    const f16* vc = vbuf[cur];
    const int keyL0 = (ks * 32 + l15) << 3;
    const int keyL1 = (ks * 32 + 16 + l15) << 3;
    const f16x8 ak00 = *(const f16x8*)(kc + quad * 1024 + keyL0);
    const f16x8 ak01 = *(const f16x8*)(kc + (4 + quad) * 1024 + keyL0);
    const f16x8 ak10 = *(const f16x8*)(kc + quad * 1024 + keyL1);
    const f16x8 ak11 = *(const f16x8*)(kc + (4 + quad) * 1024 + keyL1);

    // S^T[key][q] over this wave's 32 keys
    f32x4 s0, s1;
    {
      f32x4 z = {0.f, 0.f, 0.f, 0.f};
      z = __builtin_amdgcn_mfma_f32_16x16x32_f16(ak00, bq0, z, 0, 0, 0);
      s0 = __builtin_amdgcn_mfma_f32_16x16x32_f16(ak01, bq1, z, 0, 0, 0);
    }
    {
      f32x4 z = {0.f, 0.f, 0.f, 0.f};
      z = __builtin_amdgcn_mfma_f32_16x16x32_f16(ak10, bq0, z, 0, 0, 0);
      s1 = __builtin_amdgcn_mfma_f32_16x16x32_f16(ak11, bq1, z, 0, 0, 0);
    }

    // online softmax (query = l15, cross-quad max)
    float tmax = fmaxf(fmaxf(fmaxf(s0[0], s0[1]), fmaxf(s0[2], s0[3])),
                       fmaxf(fmaxf(s1[0], s1[1]), fmaxf(s1[2], s1[3])));
    tmax = fmaxf(tmax, __shfl_xor(tmax, 16, 64));
    tmax = fmaxf(tmax, __shfl_xor(tmax, 32, 64));
    const bool upd = tmax > m;
    const float mnew = upd ? tmax : m;

    f16x4 a0, a1;   // P fragments straight from registers
    float tsum = 0.f;
    {
      const float p0 = fexp2(s0[0] - mnew);
      const float p1 = fexp2(s0[1] - mnew);
      const float p2 = fexp2(s0[2] - mnew);
      const float p3 = fexp2(s0[3] - mnew);
      tsum += (p0 + p1) + (p2 + p3);
      a0[0] = f2h(p0); a0[1] = f2h(p1); a0[2] = f2h(p2); a0[3] = f2h(p3);
    }
    {
      const float p0 = fexp2(s1[0] - mnew);
      const float p1 = fexp2(s1[1] - mnew);
      const float p2 = fexp2(s1[2] - mnew);
      const float p3 = fexp2(s1[3] - mnew);
      tsum += (p0 + p1) + (p2 + p3);
      a1[0] = f2h(p0); a1[1] = f2h(p1); a1[2] = f2h(p2); a1[3] = f2h(p3);
    }

    if (__any(upd)) {
      const float alpha = fexp2(m - mnew);   // quad-uniform at l15=q
      lp = lp * alpha + tsum;
      const int srcbase = (lane & 48) + ((lane >> 4) << 2);
      for (int r = 0; r < 4; ++r) {
        const float ar = __shfl(alpha, srcbase + r, 64);
        for (int ct = 0; ct < 4; ++ct) o[ct][r] *= ar;
      }
    } else {
      lp += tsum;
    }
    m = mnew;

    // O += P*V via two K=16 MFMAs per ct (V b64 chunks, conflict-free)
    for (int ct = 0; ct < 4; ++ct) {
      const int cb = (ct * 16 + l15) << 2;
      const f16x4 bv0 = *(const f16x4*)(vc + ((ks * 8 + quad) << 8) + cb);
      const f16x4 bv1 = *(const f16x4*)(vc + ((ks * 8 + 4 + quad) << 8) + cb);
      o[ct] = __builtin_amdgcn_mfma_f32_16x16x16f16(a0, bv0, o[ct], 0, 0, 0);
      o[ct] = __builtin_amdgcn_mfma_f32_16x16x16f16(a1, bv1, o[ct], 0, 0, 0);
    }
    __syncthreads();   // DMA landed + all waves done with buffers
  }

  // publish per-wave online state (m quad-uniform; lp reduced across quads)
  {
    float v = lp;
    v += __shfl_xor(v, 16, 64);
    v += __shfl_xor(v, 32, 64);
    if (quad == 0) {
      ldsM[ks][qh * 16 + l15] = m;
      ldsL[ks][qh * 16 + l15] = v;
    }
  }
  __syncthreads();

  // per-query global max + denom (4 key-slices)
  if (tid < 32) {
    const float M = fmaxf(fmaxf(ldsM[0][tid], ldsM[1][tid]),
                          fmaxf(ldsM[2][tid], ldsM[3][tid]));
    const float lt = ldsL[0][tid] * fexp2(ldsM[0][tid] - M) +
                     ldsL[1][tid] * fexp2(ldsM[1][tid] - M) +
                     ldsL[2][tid] * fexp2(ldsM[2][tid] - M) +
                     ldsL[3][tid] * fexp2(ldsM[3][tid] - M);
    ldsMg[tid] = M;
    ldsInv[tid] = 1.f / lt;
  }
  __syncthreads();

  // m-aware merge of partial O across the 4 key-split waves
  for (int r = 0; r < 4; ++r) {
    const int q = qh * 16 + quad * 4 + r;
    const float sc = fexp2(ldsM[ks][q] - ldsMg[q]);
    for (int ct = 0; ct < 4; ++ct)
      atomicAdd(&ldsO[q * 65 + ct * 16 + l15], o[ct][r] * sc);
  }
  __syncthreads();

  // epilogue: y0[b][c][n] = gamma * O / l ; BN partial sums
  const float g = gam[0];
  {
    const int c = tid >> 3;              // 0..63
    const int q0 = (tid & 7) << 2;       // 0..28
    float4 v4;
    float* vp = &v4.x;
    float s1 = 0.f, s2 = 0.f;
    for (int r = 0; r < 4; ++r) {
      const float val = g * ldsO[(q0 + r) * 65 + c] * ldsInv[q0 + r];
      vp[r] = val; s1 += val; s2 += val * val;
    }
    *(float4*)(y0 + ((size_t)(b * 64 + c) << 12) + qb0 + q0) = v4;
    s1 += __shfl_xor(s1, 1, 64);
    s2 += __shfl_xor(s2, 1, 64);
    s1 += __shfl_xor(s1, 2, 64);
    s2 += __shfl_xor(s2, 2, 64);
    s1 += __shfl_xor(s1, 4, 64);
    s2 += __shfl_xor(s2, 4, 64);
    if ((tid & 7) == 0) {
      atomicAdd(&gs1[c], s1);
      atomicAdd(&gs2[c], s2);
    }
  }
}

// ---------------------------------------------------------------------------
// apply: BN(scale/shift from gs1/gs2) + residual.
// ---------------------------------------------------------------------------
__global__ __launch_bounds__(256, 2) void pam_apply(
    const float* __restrict__ y0, const float* __restrict__ x,
    const float* __restrict__ gs1, const float* __restrict__ gs2,
    const float* __restrict__ bnw, const float* __restrict__ bnb,
    float* __restrict__ out)
{
  const int i = (blockIdx.x * 256 + threadIdx.x) << 2;   // 4 elems/thread
  const int c = (i >> 12) & 63;
  const float inv_n = 1.f / 16384.f;
  const float mean = gs1[c] * inv_n;
  const float var = fmaxf(gs2[c] * inv_n - mean * mean, 0.f);
  const float sc = bnw[c] * rsqrtf(var + 1e-5f);
  const float sh = bnb[c] - mean * sc;
  const float4 y = *(const float4*)(y0 + i);
  const float4 xv = *(const float4*)(x + i);
  float4 r;
  r.x = y.x * sc + sh + xv.x;
  r.y = y.y * sc + sh + xv.y;
  r.z = y.z * sc + sh + xv.z;
  r.w = y.w * sc + sh + xv.w;
  *(float4*)(out + i) = r;
}

// ---------------------------------------------------------------------------
extern "C" void kernel_launch(void* const* d_in, const int* in_sizes, int n_in,
                              void* d_out, int out_size, void* d_ws, size_t ws_size,
                              hipStream_t stream)
{
  (void)in_sizes; (void)n_in; (void)out_size; (void)ws_size;
  const float* x   = (const float*)d_in[0];
  const float* qw  = (const float*)d_in[1];
  const float* kw  = (const float*)d_in[2];
  const float* vw  = (const float*)d_in[3];
  const float* vb  = (const float*)d_in[4];
  const float* gam = (const float*)d_in[5];
  const float* bnw = (const float*)d_in[6];
  const float* bnb = (const float*)d_in[7];

  char* ws = (char*)d_ws;
  f16*   qa  = (f16*)(ws);
  f16*   ka2 = (f16*)(ws + (2u << 20));
  f16*   va3 = (f16*)(ws + (4u << 20));
  float* y0  = (float*)(ws + (6u << 20));
  float* gs1 = (float*)(ws + (10u << 20));          // 64 floats
  float* gs2 = (float*)(ws + (10u << 20) + 256);    // 64 floats (contiguous)

  pam_pre  <<<1024, 256, 0, stream>>>(x, qw, kw, vw, vb, qa, ka2, va3, gs1);
  pam_attn <<<512, 512, 0, stream>>>(qa, ka2, va3, gam, y0, gs1, gs2);
  pam_apply<<<1024, 256, 0, stream>>>(y0, x, gs1, gs2, bnw, bnb, (float*)d_out);
}